// Round 4
// baseline (382.748 us; speedup 1.0000x reference)
//
#include <hip/hip_runtime.h>
#include <hip/hip_bf16.h>

// Problem constants
#define NN 8192
#define DD 128
#define CC 1000
#define LN2 0.69314718f
#define G_SCALE 14.42695041f   // 10/ln2 : MFMA emits log2-domain scores
#define NSTRIP 16
#define JPER   512             // 8192/16 j-columns per strip
#define NTILE  8               // JPER/64
#define LROW   128             // u16 per LDS B-row; no pad (global_load_lds is
                               // contiguous); bank conflicts killed by XOR swizzle
#define GRID_MAIN 1024         // ONE generation: 4 blocks/CU exactly
#define RED_BLOCKS 32

typedef short v8s __attribute__((ext_vector_type(8)));
typedef float v4f __attribute__((ext_vector_type(4)));
typedef unsigned short u16;
typedef unsigned int u32;

typedef __attribute__((address_space(1))) const unsigned char ga_t;
typedef __attribute__((address_space(3))) unsigned char la_t;
#define GLOAD_LDS16(g, l) __builtin_amdgcn_global_load_lds((ga_t*)(g), (la_t*)(l), 16, 0, 0)

#if __has_builtin(__builtin_amdgcn_exp2f)
#define EXP2(x) __builtin_amdgcn_exp2f(x)
#else
#define EXP2(x) exp2f(x)
#endif
#if __has_builtin(__builtin_amdgcn_logf)
#define LOG2(x) __builtin_amdgcn_logf(x)
#else
#define LOG2(x) log2f(x)
#endif

// ---- helpers -------------------------------------------------------------
static __device__ __forceinline__ float bf2f(u16 u) {
    union { float f; u32 i; } x; x.i = ((u32)u) << 16; return x.f;
}
static __device__ __forceinline__ u16 f2bf(float f) {
    u32 x = __float_as_uint(f);
    return (u16)((x + 0x7FFFu + ((x >> 16) & 1u)) >> 16);  // RNE
}
static __device__ __forceinline__ float wsum(float v) {
    #pragma unroll
    for (int m = 1; m < 64; m <<= 1) v += __shfl_xor(v, m, 64);
    return v;
}
static __device__ __forceinline__ float wmax(float v) {
    #pragma unroll
    for (int m = 1; m < 64; m <<= 1) v = fmaxf(v, __shfl_xor(v, m, 64));
    return v;
}

// ---- prep: normalize (1024 blocks) + targets/hist/zero (1 block) ---------
__global__ __launch_bounds__(256) void prep_kernel(const void* __restrict__ fs,
                                                   const void* __restrict__ ft,
                                                   const int* __restrict__ traw,
                                                   u16* __restrict__ f1, u16* __restrict__ f2,
                                                   int* __restrict__ tgt32,
                                                   int* __restrict__ ghist,
                                                   float* __restrict__ sums) {
    __shared__ int h[128];
    int b = blockIdx.x, tid = threadIdx.x;
    int w = tid >> 6, lane = tid & 63;

    if (b < 1024) {
        // ------------------- normalize path (wave per row, 4 rows) ------
        #pragma unroll
        for (int r = 0; r < 4; r++) {
            int row4 = b * 16 + w * 4 + r;        // 0..16383
            const void* src; u16* dst; float gain; int row;
            if (row4 < NN) { src = fs; dst = f1; gain = G_SCALE; row = row4; }
            else           { src = ft; dst = f2; gain = 1.0f;    row = row4 - NN; }
            u32 wb = ((const u32*)src)[(size_t)row * 64 + lane];
            unsigned e = (wb >> 7) & 0xFF;
            int isF32 = (__popcll(__ballot(e >= 100 && e <= 140)) < 32);
            float x0, x1;
            if (isF32) {
                float2 v = ((const float2*)src)[(size_t)row * 64 + lane];
                x0 = v.x; x1 = v.y;
            } else {
                x0 = bf2f((u16)(wb & 0xFFFF));
                x1 = bf2f((u16)(wb >> 16));
            }
            float ss = wsum(x0 * x0 + x1 * x1);
            float sc = gain / fmaxf(sqrtf(ss), 1e-12f);
            u32 outw = (u32)f2bf(x0 * sc) | ((u32)f2bf(x1 * sc) << 16);
            ((u32*)dst)[(size_t)row * 64 + lane] = outw;
        }
    } else {
        // ---- single block: zero accumulators, decode targets, histogram
        if (tid < 4) sums[tid] = 0.0f;            // Lsum, Jsum, done, spare
        if (tid < 128) h[tid] = 0;
        __syncthreads();
        for (int r = 0; r < 32; r++) {
            int idx = r * 256 + tid;               // target index 0..8191
            int k = (idx >> 1) & 4095;             // odd-dword probe, in-bounds both ways
            int odd = traw[2 * k + 1];
            int is32 = (__ballot(odd != 0) != 0ull);
            int t = (is32 ? traw[idx] : traw[2 * idx]) & 127;
            tgt32[idx] = t;
            atomicAdd(&h[t], 1);                   // LDS atomic, low contention
        }
        __syncthreads();
        if (tid < 128) ghist[tid] = h[tid];        // plain stores: no pre-zero needed
    }
}

// ---- fused NCE + JSD tail, SINGLE GENERATION -----------------------------
// Round-3 lesson: bx%3 interleave starved NCE to ~1.3 blocks/CU -> 65.6 us.
// Round-0 lesson: [all NCE][all JSD] ordering pays a ~21 us ragged JSD
// block-churn tail. Fix: grid = 1024 = exactly 4 blocks/CU (LDS 33 KB),
// every block does its NCE strip at full parallelism, then processes 8 JSD
// rows (2 per wave) as tail work. One generation, zero churn; JSD streaming
// overlaps NCE stragglers. __launch_bounds__(256,4) pins VGPR<=128 so the
// JSD tail's +32 live regs can't drop waves/SIMD below 4.
__global__ __launch_bounds__(256, 4) void main_kernel(const u16* __restrict__ f1,
                                                      const u16* __restrict__ f2,
                                                      const int* __restrict__ tgt,
                                                      const void* __restrict__ ls,
                                                      const void* __restrict__ lt,
                                                      float* __restrict__ Pp,
                                                      float* __restrict__ Qp,
                                                      float* __restrict__ Sp,
                                                      float* __restrict__ sums) {
    __shared__ u16 lds[2][64 * LROW];   // 2 x 16 KiB
    __shared__ float sred[4];
    int bx = blockIdx.x;
    int tid = threadIdx.x;
    int w = tid >> 6, lane = tid & 63;

    // ------------------- NCE part (all 1024 blocks) -------------------
    {
        int strip = bx & (NSTRIP - 1);
        int ib = bx >> 4;
        int quad = lane >> 4, lcol = lane & 15;
        int ibase = ib * 128 + w * 32;

        v8s a0[4], a1[4];
        #pragma unroll
        for (int t = 0; t < 4; t++) {
            int k = t * 32 + quad * 8;
            a0[t] = *(const v8s*)(f1 + (size_t)(ibase + lcol) * DD + k);
            a1[t] = *(const v8s*)(f1 + (size_t)(ibase + 16 + lcol) * DD + k);
        }
        int ti[8];
        #pragma unroll
        for (int a = 0; a < 2; a++)
            #pragma unroll
            for (int v = 0; v < 4; v++)
                ti[a * 4 + v] = tgt[ibase + a * 16 + quad * 4 + v];

        float P[8] = {}, Q[8] = {}, S[8] = {};

        // staging geometry: wave w, round r covers rows r*16 + 4w + (lane>>4)
        int rrl = 4 * w + (lane >> 4);          // row key within 16 (0..15)
        int cg = (lane & 15) ^ rrl;             // swizzled source chunk
        const u16* gb = f2 + (size_t)strip * JPER * DD + (size_t)rrl * DD + cg * 8;
        // per-wave-uniform LDS byte base for round r: (r*16 + 4w) * 256
        int ldsbase = 4 * w * 256;

        // preload tile 0
        #pragma unroll
        for (int r = 0; r < 4; r++)
            GLOAD_LDS16(gb + (size_t)r * 16 * DD,
                        (unsigned char*)lds[0] + ldsbase + r * 16 * 256);

        for (int it = 0; it < NTILE; ++it) {
            __syncthreads();   // vmcnt drain: tile `it` resident; prev reads done
            if (it + 1 < NTILE) {
                const u16* g2 = gb + (size_t)(it + 1) * 64 * DD;
                unsigned char* l2 = (unsigned char*)lds[(it + 1) & 1] + ldsbase;
                #pragma unroll
                for (int r = 0; r < 4; r++)
                    GLOAD_LDS16(g2 + (size_t)r * 16 * DD, l2 + r * 16 * 256);
            }
            int jb = strip * JPER + it * 64;
            int tj0 = tgt[jb + lcol];
            int tj1 = tgt[jb + 16 + lcol];
            int tj2 = tgt[jb + 32 + lcol];
            int tj3 = tgt[jb + 48 + lcol];

            const u16* buf = lds[it & 1];
            v4f zero = {0.f, 0.f, 0.f, 0.f};
            v4f acc[8] = {zero, zero, zero, zero, zero, zero, zero, zero};
            #pragma unroll
            for (int t = 0; t < 4; t++) {
                int s = ((quad + 4 * t) ^ lcol) * 8;      // swizzled chunk offset (u16)
                v8s b0 = *(const v8s*)(buf + (lcol)*LROW + s);
                v8s b1 = *(const v8s*)(buf + (16 + lcol) * LROW + s);
                v8s b2 = *(const v8s*)(buf + (32 + lcol) * LROW + s);
                v8s b3 = *(const v8s*)(buf + (48 + lcol) * LROW + s);
                acc[0] = __builtin_amdgcn_mfma_f32_16x16x32_bf16(a0[t], b0, acc[0], 0, 0, 0);
                acc[1] = __builtin_amdgcn_mfma_f32_16x16x32_bf16(a0[t], b1, acc[1], 0, 0, 0);
                acc[2] = __builtin_amdgcn_mfma_f32_16x16x32_bf16(a0[t], b2, acc[2], 0, 0, 0);
                acc[3] = __builtin_amdgcn_mfma_f32_16x16x32_bf16(a0[t], b3, acc[3], 0, 0, 0);
                acc[4] = __builtin_amdgcn_mfma_f32_16x16x32_bf16(a1[t], b0, acc[4], 0, 0, 0);
                acc[5] = __builtin_amdgcn_mfma_f32_16x16x32_bf16(a1[t], b1, acc[5], 0, 0, 0);
                acc[6] = __builtin_amdgcn_mfma_f32_16x16x32_bf16(a1[t], b2, acc[6], 0, 0, 0);
                acc[7] = __builtin_amdgcn_mfma_f32_16x16x32_bf16(a1[t], b3, acc[7], 0, 0, 0);
            }
            #pragma unroll
            for (int a = 0; a < 2; a++) {
                #pragma unroll
                for (int v = 0; v < 4; v++) {
                    int t_i = ti[a * 4 + v];
                    #pragma unroll
                    for (int jf = 0; jf < 4; jf++) {
                        float s2 = acc[a * 4 + jf][v];
                        float e1 = EXP2(s2);
                        int tj = (jf == 0) ? tj0 : (jf == 1) ? tj1 : (jf == 2) ? tj2 : tj3;
                        bool pos = (tj == t_i);
                        P[a * 4 + v] += e1;
                        Q[a * 4 + v] += pos ? e1 : 0.0f;
                        S[a * 4 + v] += pos ? s2 : 0.0f;
                    }
                }
            }
        }

        #pragma unroll
        for (int a = 0; a < 2; a++) {
            #pragma unroll
            for (int v = 0; v < 4; v++) {
                float p = P[a * 4 + v], q = Q[a * 4 + v], s = S[a * 4 + v];
                #pragma unroll
                for (int m = 1; m < 16; m <<= 1) {
                    p += __shfl_xor(p, m, 64);
                    q += __shfl_xor(q, m, 64);
                    s += __shfl_xor(s, m, 64);
                }
                if (lcol == 0) {
                    size_t idx = (size_t)strip * NN + ibase + a * 16 + quad * 4 + v;
                    Pp[idx] = p;   // plain stores -- NOT atomics
                    Qp[idx] = q;
                    Sp[idx] = s;
                }
            }
        }
    }

    // ------------------- JSD tail: 8 rows per block (2 per wave) ----------
    float jacc = 0.0f;
    for (int jj = 0; jj < 2; jj++) {
        int row = bx * 8 + jj * 4 + w;          // 0..8191, bijective
        u32 wb = ((const u32*)ls)[(size_t)row * 500 + lane];
        unsigned e = (wb >> 7) & 0xFF;
        int isF32 = (__popcll(__ballot(e >= 100 && e <= 140)) < 32);

        float xs[16], xt[16];
        #pragma unroll
        for (int c = 0; c < 4; c++) {
            int idx = c * 256 + lane * 4;
            if (idx < CC) {
                if (isF32) {
                    float4 a = *(const float4*)((const float*)ls + (size_t)row * CC + idx);
                    float4 bb = *(const float4*)((const float*)lt + (size_t)row * CC + idx);
                    xs[c*4+0] = a.x; xs[c*4+1] = a.y; xs[c*4+2] = a.z; xs[c*4+3] = a.w;
                    xt[c*4+0] = bb.x; xt[c*4+1] = bb.y; xt[c*4+2] = bb.z; xt[c*4+3] = bb.w;
                } else {
                    ushort4 a = *(const ushort4*)((const u16*)ls + (size_t)row * CC + idx);
                    ushort4 bb = *(const ushort4*)((const u16*)lt + (size_t)row * CC + idx);
                    xs[c*4+0] = bf2f(a.x); xs[c*4+1] = bf2f(a.y); xs[c*4+2] = bf2f(a.z); xs[c*4+3] = bf2f(a.w);
                    xt[c*4+0] = bf2f(bb.x); xt[c*4+1] = bf2f(bb.y); xt[c*4+2] = bf2f(bb.z); xt[c*4+3] = bf2f(bb.w);
                }
            } else {
                #pragma unroll
                for (int q = 0; q < 4; q++) { xs[c*4+q] = -1e30f; xt[c*4+q] = -1e30f; }
            }
        }
        // Anchor every value in a VGPR: forbids the round-2 remat pathology
        // (compiler re-reading ls/lt once per pass instead of keeping regs).
        #pragma unroll
        for (int q = 0; q < 16; q++) {
            asm volatile("" : "+v"(xs[q]));
            asm volatile("" : "+v"(xt[q]));
        }
        float ms = -1e30f, mt = -1e30f;
        #pragma unroll
        for (int q = 0; q < 16; q++) { ms = fmaxf(ms, xs[q]); mt = fmaxf(mt, xt[q]); }
        ms = wmax(ms); mt = wmax(mt);
        float es = 0.f, et = 0.f;
        #pragma unroll
        for (int q = 0; q < 16; q++) { es += __expf(xs[q] - ms); et += __expf(xt[q] - mt); }
        es = wsum(es); et = wsum(et);
        float lse_s = ms + __logf(es), lse_t = mt + __logf(et);
        float contrib = 0.f;
        #pragma unroll
        for (int q = 0; q < 16; q++) {
            float lps = xs[q] - lse_s, lpt = xt[q] - lse_t;
            contrib += (lpt - lps) * (__expf(lpt) - __expf(lps));
        }
        jacc += contrib;
    }
    jacc = wsum(jacc);
    if (lane == 0) sred[w] = jacc;
    __syncthreads();
    if (tid == 0) atomicAdd(&sums[1], sred[0] + sred[1] + sred[2] + sred[3]);
}

// ---- rowred + finalize (histogram precomputed in prep) -------------------
__global__ __launch_bounds__(256) void rowred_kernel(const float* __restrict__ Pp,
                                                     const float* __restrict__ Qp,
                                                     const float* __restrict__ Sp,
                                                     const int* __restrict__ tgt,
                                                     const int* __restrict__ ghist,
                                                     float* __restrict__ sums,
                                                     u32* __restrict__ out) {
    __shared__ float sb[4];
    __shared__ int lastf;
    int tid = threadIdx.x;

    int i = blockIdx.x * 256 + tid;
    float P = 0.f, Q = 0.f, S = 0.f;
    #pragma unroll
    for (int s = 0; s < NSTRIP; s++) {
        P += Pp[(size_t)s * NN + i];
        Q += Qp[(size_t)s * NN + i];
        S += Sp[(size_t)s * NN + i];
    }
    int cnt = ghist[tgt[i]];
    float pos = LN2 * LOG2(P) - LN2 * S / (float)cnt;
    float neg = (1.0f - Q / P) / (float)(NN - cnt);
    float l = wsum(pos + neg);
    if ((tid & 63) == 0) sb[tid >> 6] = l;
    __syncthreads();
    if (tid == 0) {
        atomicAdd(&sums[0], sb[0] + sb[1] + sb[2] + sb[3]);
        __threadfence();
        int* done = (int*)sums + 2;
        lastf = (atomicAdd(done, 1) == RED_BLOCKS - 1);
    }
    __syncthreads();
    if (!lastf) return;
    if (tid == 0) {
        float Lsum = __hip_atomic_load(&sums[0], __ATOMIC_RELAXED, __HIP_MEMORY_SCOPE_AGENT);
        float Jsum = __hip_atomic_load(&sums[1], __ATOMIC_RELAXED, __HIP_MEMORY_SCOPE_AGENT);
        float loss = (Lsum + 0.5f * Jsum) / (float)NN;
        u32 fb = __float_as_uint(loss);
        out[0] = (fb & 0xFFFF0000u) | (u32)f2bf(loss);   // dual bf16/fp32 word
    }
}

// ---- launch --------------------------------------------------------------
extern "C" void kernel_launch(void* const* d_in, const int* in_sizes, int n_in,
                              void* d_out, int out_size, void* d_ws, size_t ws_size,
                              hipStream_t stream) {
    const void* fs = d_in[0];
    const void* ft = d_in[1];
    const void* ls = d_in[2];
    const void* lt = d_in[3];
    const int* tgt_raw = (const int*)d_in[4];

    char* wsp = (char*)d_ws;
    u16*   f1    = (u16*)(wsp + 0);           // 2 MiB
    u16*   f2    = (u16*)(wsp + 2097152);     // 2 MiB
    float* Pp    = (float*)(wsp + 4194304);   // 512 KiB (16 x 8192)
    float* Qp    = (float*)(wsp + 4718592);   // 512 KiB
    float* Sp    = (float*)(wsp + 5242880);   // 512 KiB
    float* sums  = (float*)(wsp + 5767168);   // 16 B (Lsum, Jsum, done, spare)
    int*   ghist = (int*)(wsp + 5767296);     // 512 B class histogram
    int*   tgt32 = (int*)(wsp + 5768192);     // 32 KiB

    prep_kernel<<<1025, 256, 0, stream>>>(fs, ft, tgt_raw, f1, f2, tgt32, ghist, sums);
    main_kernel<<<GRID_MAIN, 256, 0, stream>>>(f1, f2, tgt32, ls, lt, Pp, Qp, Sp, sums);
    rowred_kernel<<<RED_BLOCKS, 256, 0, stream>>>(Pp, Qp, Sp, tgt32, ghist, sums,
                                                  (u32*)d_out);
}

// Round 5
// 163.548 us; speedup vs baseline: 2.3403x; 2.3403x over previous
//
#include <hip/hip_runtime.h>
#include <hip/hip_bf16.h>

// Problem constants
#define NN 8192
#define DD 128
#define CC 1000
#define LN2 0.69314718f
#define G_SCALE 14.42695041f   // 10/ln2 : MFMA emits log2-domain scores
#define NSTRIP 16
#define JPER   512             // 8192/16 j-columns per strip
#define NTILE  8               // JPER/64
#define LROW   128             // u16 per LDS B-row; no pad (global_load_lds is
                               // contiguous); bank conflicts killed by XOR swizzle
#define GRID_MAIN 1024         // ONE generation: 4 blocks/CU exactly
#define RED_BLOCKS 32

typedef short v8s __attribute__((ext_vector_type(8)));
typedef float v4f __attribute__((ext_vector_type(4)));
typedef unsigned short u16;
typedef unsigned int u32;

typedef __attribute__((address_space(1))) const unsigned char ga_t;
typedef __attribute__((address_space(3))) unsigned char la_t;
#define GLOAD_LDS16(g, l) __builtin_amdgcn_global_load_lds((ga_t*)(g), (la_t*)(l), 16, 0, 0)

#if __has_builtin(__builtin_amdgcn_exp2f)
#define EXP2(x) __builtin_amdgcn_exp2f(x)
#else
#define EXP2(x) exp2f(x)
#endif
#if __has_builtin(__builtin_amdgcn_logf)
#define LOG2(x) __builtin_amdgcn_logf(x)
#else
#define LOG2(x) log2f(x)
#endif

// ---- helpers -------------------------------------------------------------
static __device__ __forceinline__ float bf2f(u16 u) {
    union { float f; u32 i; } x; x.i = ((u32)u) << 16; return x.f;
}
static __device__ __forceinline__ u16 f2bf(float f) {
    u32 x = __float_as_uint(f);
    return (u16)((x + 0x7FFFu + ((x >> 16) & 1u)) >> 16);  // RNE
}
static __device__ __forceinline__ float wsum(float v) {
    #pragma unroll
    for (int m = 1; m < 64; m <<= 1) v += __shfl_xor(v, m, 64);
    return v;
}
static __device__ __forceinline__ float wmax(float v) {
    #pragma unroll
    for (int m = 1; m < 64; m <<= 1) v = fmaxf(v, __shfl_xor(v, m, 64));
    return v;
}

// ---- prep: normalize (1024 blocks) + targets/hist/zero (1 block) ---------
__global__ __launch_bounds__(256) void prep_kernel(const void* __restrict__ fs,
                                                   const void* __restrict__ ft,
                                                   const int* __restrict__ traw,
                                                   u16* __restrict__ f1, u16* __restrict__ f2,
                                                   int* __restrict__ tgt32,
                                                   int* __restrict__ ghist,
                                                   float* __restrict__ sums) {
    __shared__ int h[128];
    int b = blockIdx.x, tid = threadIdx.x;
    int w = tid >> 6, lane = tid & 63;

    if (b < 1024) {
        // ------------------- normalize path (wave per row, 4 rows) ------
        #pragma unroll
        for (int r = 0; r < 4; r++) {
            int row4 = b * 16 + w * 4 + r;        // 0..16383
            const void* src; u16* dst; float gain; int row;
            if (row4 < NN) { src = fs; dst = f1; gain = G_SCALE; row = row4; }
            else           { src = ft; dst = f2; gain = 1.0f;    row = row4 - NN; }
            u32 wb = ((const u32*)src)[(size_t)row * 64 + lane];
            unsigned e = (wb >> 7) & 0xFF;
            int isF32 = (__popcll(__ballot(e >= 100 && e <= 140)) < 32);
            float x0, x1;
            if (isF32) {
                float2 v = ((const float2*)src)[(size_t)row * 64 + lane];
                x0 = v.x; x1 = v.y;
            } else {
                x0 = bf2f((u16)(wb & 0xFFFF));
                x1 = bf2f((u16)(wb >> 16));
            }
            float ss = wsum(x0 * x0 + x1 * x1);
            float sc = gain / fmaxf(sqrtf(ss), 1e-12f);
            u32 outw = (u32)f2bf(x0 * sc) | ((u32)f2bf(x1 * sc) << 16);
            ((u32*)dst)[(size_t)row * 64 + lane] = outw;
        }
    } else {
        // ---- single block: zero accumulators, decode targets, histogram
        if (tid < 4) sums[tid] = 0.0f;            // Lsum, Jsum, done, spare
        if (tid < 128) h[tid] = 0;
        __syncthreads();
        for (int r = 0; r < 32; r++) {
            int idx = r * 256 + tid;               // target index 0..8191
            int k = (idx >> 1) & 4095;             // odd-dword probe, in-bounds both ways
            int odd = traw[2 * k + 1];
            int is32 = (__ballot(odd != 0) != 0ull);
            int t = (is32 ? traw[idx] : traw[2 * idx]) & 127;
            tgt32[idx] = t;
            atomicAdd(&h[t], 1);                   // LDS atomic, low contention
        }
        __syncthreads();
        if (tid < 128) ghist[tid] = h[tid];        // plain stores: no pre-zero needed
    }
}

// ---- fused NCE + JSD tail, SINGLE GENERATION -----------------------------
// Round-4 post-mortem: __launch_bounds__(256,4) drove the allocator to
// VGPR=64 and everything (NCE accs + 32 anchored JSD floats) spilled to
// scratch -> 856 MB HBM spill traffic, 270 us. The tail-fusion structure
// itself is correct (absmax=0) and the anchors coexist with a healthy
// budget (round 3: VGPR=76, zero spill). Fix: plain __launch_bounds__(256);
// occupancy is LDS-limited to 4 blocks/CU anyway (33 KB), so the VGPR cap
// bought nothing and cost everything.
// Schedule: grid = 1024 = one generation; each block runs its NCE strip at
// full 4/CU parallelism, then streams 8 JSD rows (2 per wave) as tail work.
// JSD's 65 MB HBM streaming starts per-block as its strip finishes -- no
// dispatch churn (round-0's 21 us ragged backfill), no NCE starvation
// (round-3's 1.3 blocks/CU interleave).
__global__ __launch_bounds__(256) void main_kernel(const u16* __restrict__ f1,
                                                   const u16* __restrict__ f2,
                                                   const int* __restrict__ tgt,
                                                   const void* __restrict__ ls,
                                                   const void* __restrict__ lt,
                                                   float* __restrict__ Pp,
                                                   float* __restrict__ Qp,
                                                   float* __restrict__ Sp,
                                                   float* __restrict__ sums) {
    __shared__ u16 lds[2][64 * LROW];   // 2 x 16 KiB
    __shared__ float sred[4];
    int bx = blockIdx.x;
    int tid = threadIdx.x;
    int w = tid >> 6, lane = tid & 63;

    // ------------------- NCE part (all 1024 blocks) -------------------
    {
        int strip = bx & (NSTRIP - 1);
        int ib = bx >> 4;
        int quad = lane >> 4, lcol = lane & 15;
        int ibase = ib * 128 + w * 32;

        v8s a0[4], a1[4];
        #pragma unroll
        for (int t = 0; t < 4; t++) {
            int k = t * 32 + quad * 8;
            a0[t] = *(const v8s*)(f1 + (size_t)(ibase + lcol) * DD + k);
            a1[t] = *(const v8s*)(f1 + (size_t)(ibase + 16 + lcol) * DD + k);
        }
        int ti[8];
        #pragma unroll
        for (int a = 0; a < 2; a++)
            #pragma unroll
            for (int v = 0; v < 4; v++)
                ti[a * 4 + v] = tgt[ibase + a * 16 + quad * 4 + v];

        float P[8] = {}, Q[8] = {}, S[8] = {};

        // staging geometry: wave w, round r covers rows r*16 + 4w + (lane>>4)
        int rrl = 4 * w + (lane >> 4);          // row key within 16 (0..15)
        int cg = (lane & 15) ^ rrl;             // swizzled source chunk
        const u16* gb = f2 + (size_t)strip * JPER * DD + (size_t)rrl * DD + cg * 8;
        // per-wave-uniform LDS byte base for round r: (r*16 + 4w) * 256
        int ldsbase = 4 * w * 256;

        // preload tile 0
        #pragma unroll
        for (int r = 0; r < 4; r++)
            GLOAD_LDS16(gb + (size_t)r * 16 * DD,
                        (unsigned char*)lds[0] + ldsbase + r * 16 * 256);

        for (int it = 0; it < NTILE; ++it) {
            __syncthreads();   // vmcnt drain: tile `it` resident; prev reads done
            if (it + 1 < NTILE) {
                const u16* g2 = gb + (size_t)(it + 1) * 64 * DD;
                unsigned char* l2 = (unsigned char*)lds[(it + 1) & 1] + ldsbase;
                #pragma unroll
                for (int r = 0; r < 4; r++)
                    GLOAD_LDS16(g2 + (size_t)r * 16 * DD, l2 + r * 16 * 256);
            }
            int jb = strip * JPER + it * 64;
            int tj0 = tgt[jb + lcol];
            int tj1 = tgt[jb + 16 + lcol];
            int tj2 = tgt[jb + 32 + lcol];
            int tj3 = tgt[jb + 48 + lcol];

            const u16* buf = lds[it & 1];
            v4f zero = {0.f, 0.f, 0.f, 0.f};
            v4f acc[8] = {zero, zero, zero, zero, zero, zero, zero, zero};
            #pragma unroll
            for (int t = 0; t < 4; t++) {
                int s = ((quad + 4 * t) ^ lcol) * 8;      // swizzled chunk offset (u16)
                v8s b0 = *(const v8s*)(buf + (lcol)*LROW + s);
                v8s b1 = *(const v8s*)(buf + (16 + lcol) * LROW + s);
                v8s b2 = *(const v8s*)(buf + (32 + lcol) * LROW + s);
                v8s b3 = *(const v8s*)(buf + (48 + lcol) * LROW + s);
                acc[0] = __builtin_amdgcn_mfma_f32_16x16x32_bf16(a0[t], b0, acc[0], 0, 0, 0);
                acc[1] = __builtin_amdgcn_mfma_f32_16x16x32_bf16(a0[t], b1, acc[1], 0, 0, 0);
                acc[2] = __builtin_amdgcn_mfma_f32_16x16x32_bf16(a0[t], b2, acc[2], 0, 0, 0);
                acc[3] = __builtin_amdgcn_mfma_f32_16x16x32_bf16(a0[t], b3, acc[3], 0, 0, 0);
                acc[4] = __builtin_amdgcn_mfma_f32_16x16x32_bf16(a1[t], b0, acc[4], 0, 0, 0);
                acc[5] = __builtin_amdgcn_mfma_f32_16x16x32_bf16(a1[t], b1, acc[5], 0, 0, 0);
                acc[6] = __builtin_amdgcn_mfma_f32_16x16x32_bf16(a1[t], b2, acc[6], 0, 0, 0);
                acc[7] = __builtin_amdgcn_mfma_f32_16x16x32_bf16(a1[t], b3, acc[7], 0, 0, 0);
            }
            #pragma unroll
            for (int a = 0; a < 2; a++) {
                #pragma unroll
                for (int v = 0; v < 4; v++) {
                    int t_i = ti[a * 4 + v];
                    #pragma unroll
                    for (int jf = 0; jf < 4; jf++) {
                        float s2 = acc[a * 4 + jf][v];
                        float e1 = EXP2(s2);
                        int tj = (jf == 0) ? tj0 : (jf == 1) ? tj1 : (jf == 2) ? tj2 : tj3;
                        bool pos = (tj == t_i);
                        P[a * 4 + v] += e1;
                        Q[a * 4 + v] += pos ? e1 : 0.0f;
                        S[a * 4 + v] += pos ? s2 : 0.0f;
                    }
                }
            }
        }

        #pragma unroll
        for (int a = 0; a < 2; a++) {
            #pragma unroll
            for (int v = 0; v < 4; v++) {
                float p = P[a * 4 + v], q = Q[a * 4 + v], s = S[a * 4 + v];
                #pragma unroll
                for (int m = 1; m < 16; m <<= 1) {
                    p += __shfl_xor(p, m, 64);
                    q += __shfl_xor(q, m, 64);
                    s += __shfl_xor(s, m, 64);
                }
                if (lcol == 0) {
                    size_t idx = (size_t)strip * NN + ibase + a * 16 + quad * 4 + v;
                    Pp[idx] = p;   // plain stores -- NOT atomics
                    Qp[idx] = q;
                    Sp[idx] = s;
                }
            }
        }
    }

    // ------------------- JSD tail: 8 rows per block (2 per wave) ----------
    float jacc = 0.0f;
    for (int jj = 0; jj < 2; jj++) {
        int row = bx * 8 + jj * 4 + w;          // 0..8191, bijective
        u32 wb = ((const u32*)ls)[(size_t)row * 500 + lane];
        unsigned e = (wb >> 7) & 0xFF;
        int isF32 = (__popcll(__ballot(e >= 100 && e <= 140)) < 32);

        float xs[16], xt[16];
        #pragma unroll
        for (int c = 0; c < 4; c++) {
            int idx = c * 256 + lane * 4;
            if (idx < CC) {
                if (isF32) {
                    float4 a = *(const float4*)((const float*)ls + (size_t)row * CC + idx);
                    float4 bb = *(const float4*)((const float*)lt + (size_t)row * CC + idx);
                    xs[c*4+0] = a.x; xs[c*4+1] = a.y; xs[c*4+2] = a.z; xs[c*4+3] = a.w;
                    xt[c*4+0] = bb.x; xt[c*4+1] = bb.y; xt[c*4+2] = bb.z; xt[c*4+3] = bb.w;
                } else {
                    ushort4 a = *(const ushort4*)((const u16*)ls + (size_t)row * CC + idx);
                    ushort4 bb = *(const ushort4*)((const u16*)lt + (size_t)row * CC + idx);
                    xs[c*4+0] = bf2f(a.x); xs[c*4+1] = bf2f(a.y); xs[c*4+2] = bf2f(a.z); xs[c*4+3] = bf2f(a.w);
                    xt[c*4+0] = bf2f(bb.x); xt[c*4+1] = bf2f(bb.y); xt[c*4+2] = bf2f(bb.z); xt[c*4+3] = bf2f(bb.w);
                }
            } else {
                #pragma unroll
                for (int q = 0; q < 4; q++) { xs[c*4+q] = -1e30f; xt[c*4+q] = -1e30f; }
            }
        }
        // Anchor every value in a VGPR: forbids the round-2 remat pathology
        // (compiler re-reading ls/lt once per pass instead of keeping regs).
        // Safe at a healthy register budget (round 3: VGPR=76, zero spill).
        #pragma unroll
        for (int q = 0; q < 16; q++) {
            asm volatile("" : "+v"(xs[q]));
            asm volatile("" : "+v"(xt[q]));
        }
        float ms = -1e30f, mt = -1e30f;
        #pragma unroll
        for (int q = 0; q < 16; q++) { ms = fmaxf(ms, xs[q]); mt = fmaxf(mt, xt[q]); }
        ms = wmax(ms); mt = wmax(mt);
        float es = 0.f, et = 0.f;
        #pragma unroll
        for (int q = 0; q < 16; q++) { es += __expf(xs[q] - ms); et += __expf(xt[q] - mt); }
        es = wsum(es); et = wsum(et);
        float lse_s = ms + __logf(es), lse_t = mt + __logf(et);
        float contrib = 0.f;
        #pragma unroll
        for (int q = 0; q < 16; q++) {
            float lps = xs[q] - lse_s, lpt = xt[q] - lse_t;
            contrib += (lpt - lps) * (__expf(lpt) - __expf(lps));
        }
        jacc += contrib;
    }
    jacc = wsum(jacc);
    if (lane == 0) sred[w] = jacc;
    __syncthreads();
    if (tid == 0) atomicAdd(&sums[1], sred[0] + sred[1] + sred[2] + sred[3]);
}

// ---- rowred + finalize (histogram precomputed in prep) -------------------
__global__ __launch_bounds__(256) void rowred_kernel(const float* __restrict__ Pp,
                                                     const float* __restrict__ Qp,
                                                     const float* __restrict__ Sp,
                                                     const int* __restrict__ tgt,
                                                     const int* __restrict__ ghist,
                                                     float* __restrict__ sums,
                                                     u32* __restrict__ out) {
    __shared__ float sb[4];
    __shared__ int lastf;
    int tid = threadIdx.x;

    int i = blockIdx.x * 256 + tid;
    float P = 0.f, Q = 0.f, S = 0.f;
    #pragma unroll
    for (int s = 0; s < NSTRIP; s++) {
        P += Pp[(size_t)s * NN + i];
        Q += Qp[(size_t)s * NN + i];
        S += Sp[(size_t)s * NN + i];
    }
    int cnt = ghist[tgt[i]];
    float pos = LN2 * LOG2(P) - LN2 * S / (float)cnt;
    float neg = (1.0f - Q / P) / (float)(NN - cnt);
    float l = wsum(pos + neg);
    if ((tid & 63) == 0) sb[tid >> 6] = l;
    __syncthreads();
    if (tid == 0) {
        atomicAdd(&sums[0], sb[0] + sb[1] + sb[2] + sb[3]);
        __threadfence();
        int* done = (int*)sums + 2;
        lastf = (atomicAdd(done, 1) == RED_BLOCKS - 1);
    }
    __syncthreads();
    if (!lastf) return;
    if (tid == 0) {
        float Lsum = __hip_atomic_load(&sums[0], __ATOMIC_RELAXED, __HIP_MEMORY_SCOPE_AGENT);
        float Jsum = __hip_atomic_load(&sums[1], __ATOMIC_RELAXED, __HIP_MEMORY_SCOPE_AGENT);
        float loss = (Lsum + 0.5f * Jsum) / (float)NN;
        u32 fb = __float_as_uint(loss);
        out[0] = (fb & 0xFFFF0000u) | (u32)f2bf(loss);   // dual bf16/fp32 word
    }
}

// ---- launch --------------------------------------------------------------
extern "C" void kernel_launch(void* const* d_in, const int* in_sizes, int n_in,
                              void* d_out, int out_size, void* d_ws, size_t ws_size,
                              hipStream_t stream) {
    const void* fs = d_in[0];
    const void* ft = d_in[1];
    const void* ls = d_in[2];
    const void* lt = d_in[3];
    const int* tgt_raw = (const int*)d_in[4];

    char* wsp = (char*)d_ws;
    u16*   f1    = (u16*)(wsp + 0);           // 2 MiB
    u16*   f2    = (u16*)(wsp + 2097152);     // 2 MiB
    float* Pp    = (float*)(wsp + 4194304);   // 512 KiB (16 x 8192)
    float* Qp    = (float*)(wsp + 4718592);   // 512 KiB
    float* Sp    = (float*)(wsp + 5242880);   // 512 KiB
    float* sums  = (float*)(wsp + 5767168);   // 16 B (Lsum, Jsum, done, spare)
    int*   ghist = (int*)(wsp + 5767296);     // 512 B class histogram
    int*   tgt32 = (int*)(wsp + 5768192);     // 32 KiB

    prep_kernel<<<1025, 256, 0, stream>>>(fs, ft, tgt_raw, f1, f2, tgt32, ghist, sums);
    main_kernel<<<GRID_MAIN, 256, 0, stream>>>(f1, f2, tgt32, ls, lt, Pp, Qp, Sp, sums);
    rowred_kernel<<<RED_BLOCKS, 256, 0, stream>>>(Pp, Qp, Sp, tgt32, ghist, sums,
                                                  (u32*)d_out);
}